// Round 1
// baseline (599.564 us; speedup 1.0000x reference)
//
#include <hip/hip_runtime.h>

// ---------------------------------------------------------------------------
// MaskedSuperAttention (agent attention), B=4 N=16384 C=512 H=8 HD=64 NA=32
// Pipeline (all bf16 MFMA, f32 accumulate):
//   k_cvt_x   : x f32 -> xbf bf16
//   k_w_t     : Wq,Wk,Wv,Wproj f32 [k][n] -> Wt bf16 [n][k] (transposed)
//   k_pack_a  : agent_tokens -> abf [h][32][64] bf16
//   k_qkv     : Q,K (row layout) and V (transposed [d][n]) = xbf @ W
//   k_agent   : per (b,h): online max/sumexp over 16384 keys, then
//               recompute scores + P@V -> agent_v bf16 [32][64]
//   k_avp     : AVP[b,h] = agent_v @ Wproj slice  -> AVPt [b][j][256] bf16
//   k_qattn   : softmax(q . a * scale) -> Qattn [tok][256] bf16
//   k_out     : out = (Qattn @ AVPt) * keymask   (K=256 GEMM, f32 out)
// Workspace: ~261 MiB. Qattn aliases xbf (dead after k_qkv).
// ---------------------------------------------------------------------------

typedef float  f32x4   __attribute__((ext_vector_type(4)));
typedef short  bf16x8  __attribute__((ext_vector_type(8)));
typedef unsigned short u16x4 __attribute__((ext_vector_type(4)));
typedef unsigned short u16x8 __attribute__((ext_vector_type(8)));

#define MFMA16(a, b, c) __builtin_amdgcn_mfma_f32_16x16x32_bf16((a), (b), (c), 0, 0, 0)

__device__ __forceinline__ unsigned short f2bf(float f) {
    unsigned u = __builtin_bit_cast(unsigned, f);
    u += 0x7FFFu + ((u >> 16) & 1u);        // RTNE
    return (unsigned short)(u >> 16);
}
__device__ __forceinline__ float bf2f(unsigned short h) {
    unsigned u = ((unsigned)h) << 16;
    return __builtin_bit_cast(float, u);
}

// ------------------------------- k_cvt_x -----------------------------------
__global__ __launch_bounds__(256) void k_cvt_x(const float* __restrict__ x,
                                               unsigned short* __restrict__ xbf) {
    size_t i = ((size_t)blockIdx.x * 256 + threadIdx.x) * 8;
    float4 v0 = *(const float4*)(x + i);
    float4 v1 = *(const float4*)(x + i + 4);
    u16x8 o;
    o[0] = f2bf(v0.x); o[1] = f2bf(v0.y); o[2] = f2bf(v0.z); o[3] = f2bf(v0.w);
    o[4] = f2bf(v1.x); o[5] = f2bf(v1.y); o[6] = f2bf(v1.z); o[7] = f2bf(v1.w);
    *(u16x8*)(xbf + i) = o;
}

// ------------------------------- k_w_t --------------------------------------
// Wt[z][n][k] = W_z[k][n], bf16.  grid (16,16,4), block 256
__global__ __launch_bounds__(256) void k_w_t(const float* __restrict__ Wq,
                                             const float* __restrict__ Wk,
                                             const float* __restrict__ Wv,
                                             const float* __restrict__ Wp,
                                             unsigned short* __restrict__ Wt) {
    __shared__ float t[32][33];
    const int z = blockIdx.z;
    const float* src = (z == 0) ? Wq : (z == 1) ? Wk : (z == 2) ? Wv : Wp;
    unsigned short* dst = Wt + (size_t)z * 262144;
    const int k0 = blockIdx.y * 32, n0 = blockIdx.x * 32;
#pragma unroll
    for (int j = 0; j < 4; ++j) {
        int i = threadIdx.x + 256 * j;
        int ky = i >> 5, nx = i & 31;
        t[ky][nx] = src[(size_t)(k0 + ky) * 512 + n0 + nx];
    }
    __syncthreads();
#pragma unroll
    for (int j = 0; j < 4; ++j) {
        int i = threadIdx.x + 256 * j;
        int ny = i >> 5, kx = i & 31;
        dst[(size_t)(n0 + ny) * 512 + k0 + kx] = f2bf(t[kx][ny]);
    }
}

// ------------------------------- k_pack_a -----------------------------------
// abf[h][ag][d] = agent_tokens[ag][h*64+d], bf16.  grid 64, block 256
__global__ __launch_bounds__(256) void k_pack_a(const float* __restrict__ at,
                                                unsigned short* __restrict__ abf) {
    int idx = threadIdx.x + blockIdx.x * 256;       // 0..16383
    int h = idx >> 11, ag = (idx >> 6) & 31, d = idx & 63;
    abf[idx] = f2bf(at[ag * 512 + h * 64 + d]);
}

// ------------------------------- k_qkv ---------------------------------------
// Q,K,V = xbf @ Wt  (BM=128, BN=64, BK=32, 4 waves, wave = 32 tok x 64 n)
// grid (8 n-tiles, 512 m-tiles), block 256
__global__ __launch_bounds__(256) void k_qkv(const unsigned short* __restrict__ xbf,
                                             const unsigned short* __restrict__ Wqt,
                                             const unsigned short* __restrict__ Wkt,
                                             const unsigned short* __restrict__ Wvt,
                                             unsigned short* __restrict__ Qbf,
                                             unsigned short* __restrict__ Kbf,
                                             unsigned short* __restrict__ Vt) {
    __shared__ __align__(16) unsigned char Asm[128 * 64];
    __shared__ __align__(16) unsigned char Bsm[3][64 * 64];
    const int tid = threadIdx.x;
    const int l = tid & 63, wid = tid >> 6;
    const int nt = blockIdx.x, mt = blockIdx.y;
    const int m0 = mt * 128, n0 = nt * 64;
    const int g = l >> 4, lr = l & 15;

    f32x4 acc[3][2][4] = {};

    for (int ks = 0; ks < 16; ++ks) {
        // stage A tile [128 tok][32 k] (f32-free: xbf already bf16)
#pragma unroll
        for (int j = 0; j < 2; ++j) {
            int i = tid + 256 * j;
            int row = i >> 2, c = i & 3;
            u16x8 v = *(const u16x8*)(xbf + (size_t)(m0 + row) * 512 + ks * 32 + c * 8);
            *(u16x8*)(Asm + row * 64 + ((c ^ (row & 3)) << 4)) = v;
        }
        // stage B tiles [64 n][32 k] x3
        {
            int row = tid >> 2, c = tid & 3;
            size_t gof = (size_t)(n0 + row) * 512 + ks * 32 + c * 8;
            int lof = row * 64 + ((c ^ (row & 3)) << 4);
            *(u16x8*)(Bsm[0] + lof) = *(const u16x8*)(Wqt + gof);
            *(u16x8*)(Bsm[1] + lof) = *(const u16x8*)(Wkt + gof);
            *(u16x8*)(Bsm[2] + lof) = *(const u16x8*)(Wvt + gof);
        }
        __syncthreads();
        bf16x8 af[2];
#pragma unroll
        for (int mf = 0; mf < 2; ++mf) {
            int row = wid * 32 + mf * 16 + lr;
            af[mf] = *(const bf16x8*)(Asm + row * 64 + ((g ^ (row & 3)) << 4));
        }
#pragma unroll
        for (int mat = 0; mat < 3; ++mat) {
#pragma unroll
            for (int nf = 0; nf < 4; ++nf) {
                int row = nf * 16 + lr;
                bf16x8 bfr = *(const bf16x8*)(Bsm[mat] + row * 64 + ((g ^ (row & 3)) << 4));
#pragma unroll
                for (int mf = 0; mf < 2; ++mf)
                    acc[mat][mf][nf] = MFMA16(af[mf], bfr, acc[mat][mf][nf]);
            }
        }
        __syncthreads();
    }

    // epilogue: Q,K row layout; V transposed [b][d][n]
    const int b = m0 >> 14;
    const int nloc0 = m0 & 16383;
#pragma unroll
    for (int mf = 0; mf < 2; ++mf) {
#pragma unroll
        for (int nf = 0; nf < 4; ++nf) {
            int trow = wid * 32 + mf * 16 + g * 4;
            int d = n0 + nf * 16 + lr;
#pragma unroll
            for (int r = 0; r < 4; ++r) {
                size_t o = (size_t)(m0 + trow + r) * 512 + d;
                Qbf[o] = f2bf(acc[0][mf][nf][r]);
                Kbf[o] = f2bf(acc[1][mf][nf][r]);
            }
            u16x4 vv;
            vv[0] = f2bf(acc[2][mf][nf][0]); vv[1] = f2bf(acc[2][mf][nf][1]);
            vv[2] = f2bf(acc[2][mf][nf][2]); vv[3] = f2bf(acc[2][mf][nf][3]);
            *(u16x4*)(Vt + ((size_t)(b * 512 + d)) * 16384 + nloc0 + trow) = vv;
        }
    }
}

// ------------------------------- k_agent -------------------------------------
// per (b,h): M/L over all keys (online), then P = exp(s-M)/L, agent_v = P @ V.
// grid 32, block 512 (8 waves, each wave owns 2048 tokens)
__global__ __launch_bounds__(512) void k_agent(const unsigned short* __restrict__ Kbf,
                                               const unsigned short* __restrict__ Vt,
                                               const unsigned short* __restrict__ abf,
                                               const int* __restrict__ mask,
                                               unsigned short* __restrict__ avbf) {
    __shared__ __align__(16) unsigned char Psm[8][2048];
    __shared__ float mls[8][32][2];
    __shared__ float fml[32][2];
    __shared__ float avs[8][2048];
    const int tid = threadIdx.x, l = tid & 63, wid = tid >> 6;
    const int bh = blockIdx.x, b = bh >> 3, h = bh & 7;
    const int g = l >> 4, lr = l & 15;

    // hoisted agent A-fragments (constant over tokens)
    bf16x8 af[2][2];
#pragma unroll
    for (int mf = 0; mf < 2; ++mf)
#pragma unroll
        for (int ks = 0; ks < 2; ++ks)
            af[mf][ks] = *(const bf16x8*)(abf + (size_t)h * 2048 + (mf * 16 + lr) * 64 + ks * 32 + g * 8);

    const int maskbase = b * 16384;
    const size_t kbase = (size_t)(b * 16384) * 512 + h * 64;

    // ---- phase 1: online (max, sumexp) ----
    float m8[8], l8[8];
#pragma unroll
    for (int s = 0; s < 8; ++s) { m8[s] = -3.0e38f; l8[s] = 0.f; }
#pragma unroll 4
    for (int it = 0; it < 128; ++it) {
        int tokn = wid * 2048 + it * 16 + lr;
        bf16x8 b0 = *(const bf16x8*)(Kbf + kbase + (size_t)tokn * 512 + g * 8);
        bf16x8 b1 = *(const bf16x8*)(Kbf + kbase + (size_t)tokn * 512 + 32 + g * 8);
        int mv = mask[maskbase + tokn];
        f32x4 z = {0.f, 0.f, 0.f, 0.f};
        f32x4 a0 = MFMA16(af[0][0], b0, z); a0 = MFMA16(af[0][1], b1, a0);
        f32x4 a1 = MFMA16(af[1][0], b0, z); a1 = MFMA16(af[1][1], b1, a1);
#pragma unroll
        for (int s = 0; s < 8; ++s) {
            float sv = (s < 4) ? a0[s & 3] : a1[s & 3];
            sv = (mv > 0) ? sv * 0.125f : -1.0e9f;
            float mn = fmaxf(m8[s], sv);
            l8[s] = l8[s] * __expf(m8[s] - mn) + __expf(sv - mn);
            m8[s] = mn;
        }
    }
    // reduce across the 16 token-lanes
#pragma unroll
    for (int k = 1; k < 16; k <<= 1) {
#pragma unroll
        for (int s = 0; s < 8; ++s) {
            float mo = __shfl_xor(m8[s], k);
            float lo = __shfl_xor(l8[s], k);
            float mn = fmaxf(m8[s], mo);
            l8[s] = l8[s] * __expf(m8[s] - mn) + lo * __expf(mo - mn);
            m8[s] = mn;
        }
    }
    if (lr == 0) {
#pragma unroll
        for (int s = 0; s < 8; ++s) {
            int ag = (s >> 2) * 16 + g * 4 + (s & 3);
            mls[wid][ag][0] = m8[s];
            mls[wid][ag][1] = l8[s];
        }
    }
    __syncthreads();
    if (tid < 32) {
        float M = -3.0e38f, L = 0.f;
#pragma unroll
        for (int w = 0; w < 8; ++w) {
            float mo = mls[w][tid][0], lo = mls[w][tid][1];
            float mn = fmaxf(M, mo);
            L = L * __expf(M - mn) + lo * __expf(mo - mn);
            M = mn;
        }
        fml[tid][0] = M;
        fml[tid][1] = 1.0f / L;
    }
    __syncthreads();
    float Mr[8], iL[8];
#pragma unroll
    for (int s = 0; s < 8; ++s) {
        int ag = (s >> 2) * 16 + g * 4 + (s & 3);
        Mr[s] = fml[ag][0]; iL[s] = fml[ag][1];
    }

    // ---- phase 2: recompute P, accumulate P @ V ----
    f32x4 pv[2][4] = {};
    unsigned char* Pw = &Psm[wid][0];
    const size_t vbase = ((size_t)b * 512 + h * 64) * 16384;
#pragma unroll 2
    for (int it = 0; it < 64; ++it) {
        int n0 = wid * 2048 + it * 32;
#pragma unroll
        for (int half = 0; half < 2; ++half) {
            int tokn = n0 + half * 16 + lr;
            bf16x8 b0 = *(const bf16x8*)(Kbf + kbase + (size_t)tokn * 512 + g * 8);
            bf16x8 b1 = *(const bf16x8*)(Kbf + kbase + (size_t)tokn * 512 + 32 + g * 8);
            int mv = mask[maskbase + tokn];
            f32x4 z = {0.f, 0.f, 0.f, 0.f};
            f32x4 a0 = MFMA16(af[0][0], b0, z); a0 = MFMA16(af[0][1], b1, a0);
            f32x4 a1 = MFMA16(af[1][0], b0, z); a1 = MFMA16(af[1][1], b1, a1);
            int tk = half * 16 + lr;
#pragma unroll
            for (int s = 0; s < 8; ++s) {
                float sv = (s < 4) ? a0[s & 3] : a1[s & 3];
                sv = (mv > 0) ? sv * 0.125f : -1.0e9f;
                float p = __expf(sv - Mr[s]) * iL[s];
                int ag = (s >> 2) * 16 + g * 4 + (s & 3);
                *(unsigned short*)(Pw + ag * 64 + ((2 * tk) ^ (((ag >> 2) & 3) << 4))) = f2bf(p);
            }
        }
        bf16x8 pa[2];
#pragma unroll
        for (int mf = 0; mf < 2; ++mf) {
            int ag = mf * 16 + lr;
            pa[mf] = *(const bf16x8*)(Pw + ag * 64 + ((g * 16) ^ (((ag >> 2) & 3) << 4)));
        }
#pragma unroll
        for (int nf = 0; nf < 4; ++nf) {
            int d = nf * 16 + lr;
            bf16x8 bv = *(const bf16x8*)(Vt + vbase + (size_t)d * 16384 + n0 + g * 8);
#pragma unroll
            for (int mf = 0; mf < 2; ++mf)
                pv[mf][nf] = MFMA16(pa[mf], bv, pv[mf][nf]);
        }
    }
    // cross-wave reduction of agent_v
#pragma unroll
    for (int mf = 0; mf < 2; ++mf)
#pragma unroll
        for (int nf = 0; nf < 4; ++nf)
#pragma unroll
            for (int r = 0; r < 4; ++r) {
                int ag = mf * 16 + g * 4 + r;
                int d = nf * 16 + lr;
                avs[wid][ag * 64 + d] = pv[mf][nf][r];
            }
    __syncthreads();
#pragma unroll
    for (int j = 0; j < 4; ++j) {
        int idx = tid + 512 * j;
        float v = avs[0][idx] + avs[1][idx] + avs[2][idx] + avs[3][idx]
                + avs[4][idx] + avs[5][idx] + avs[6][idx] + avs[7][idx];
        avbf[(size_t)bh * 2048 + idx] = f2bf(v);
    }
}

// ------------------------------- k_avp ----------------------------------------
// AVPt[b][j][h*32+ag] = sum_d agent_v[b,h,ag,d] * Wproj[h*64+d][j]
// grid 32 (b,h), block 64 (one wave)
__global__ __launch_bounds__(64) void k_avp(const unsigned short* __restrict__ avbf,
                                            const unsigned short* __restrict__ Wpt,
                                            unsigned short* __restrict__ AVPt) {
    const int l = threadIdx.x & 63;
    const int bh = blockIdx.x, b = bh >> 3, h = bh & 7;
    const int g = l >> 4, lr = l & 15;
    bf16x8 avf[2][2];
#pragma unroll
    for (int mf = 0; mf < 2; ++mf)
#pragma unroll
        for (int ks = 0; ks < 2; ++ks)
            avf[mf][ks] = *(const bf16x8*)(avbf + (size_t)bh * 2048 + (mf * 16 + lr) * 64 + ks * 32 + g * 8);
#pragma unroll 4
    for (int nf = 0; nf < 32; ++nf) {
        int j = nf * 16 + lr;
        bf16x8 w0 = *(const bf16x8*)(Wpt + (size_t)j * 512 + h * 64 + g * 8);
        bf16x8 w1 = *(const bf16x8*)(Wpt + (size_t)j * 512 + h * 64 + 32 + g * 8);
#pragma unroll
        for (int mf = 0; mf < 2; ++mf) {
            f32x4 z = {0.f, 0.f, 0.f, 0.f};
            f32x4 acc = MFMA16(avf[mf][0], w0, z);
            acc = MFMA16(avf[mf][1], w1, acc);
            u16x4 o;
            o[0] = f2bf(acc[0]); o[1] = f2bf(acc[1]); o[2] = f2bf(acc[2]); o[3] = f2bf(acc[3]);
            *(u16x4*)(AVPt + (size_t)b * 131072 + (size_t)j * 256 + h * 32 + mf * 16 + g * 4) = o;
        }
    }
}

// ------------------------------- k_qattn ---------------------------------------
// Qattn[tok][h*32+ag] = softmax_ag(q[tok,h,:] . a[h,ag,:] * scale), bf16.
// grid 2048, block 256; one thread = one (tok, head)
__global__ __launch_bounds__(256) void k_qattn(const unsigned short* __restrict__ Qbf,
                                               const unsigned short* __restrict__ abf,
                                               unsigned short* __restrict__ Qattn) {
    __shared__ __align__(16) unsigned short a_s[16384];
#pragma unroll
    for (int j = 0; j < 8; ++j) {
        int idx = (threadIdx.x + 256 * j) * 8;
        *(u16x8*)(a_s + idx) = *(const u16x8*)(abf + idx);
    }
    __syncthreads();
    int pair = blockIdx.x * 256 + threadIdx.x;
    int tok = pair >> 3, h = pair & 7;
    float logit[32];
#pragma unroll
    for (int a = 0; a < 32; ++a) logit[a] = 0.f;
    const unsigned short* qp = Qbf + (size_t)tok * 512 + h * 64;
    for (int db = 0; db < 8; ++db) {
        u16x8 q8 = *(const u16x8*)(qp + db * 8);
        float qf[8];
#pragma unroll
        for (int i = 0; i < 8; ++i) qf[i] = bf2f(q8[i]) * 0.125f;   // fold scale
#pragma unroll
        for (int a = 0; a < 32; ++a) {
            u16x8 a8 = *(const u16x8*)(a_s + (h * 32 + a) * 64 + db * 8);
#pragma unroll
            for (int i = 0; i < 8; ++i) logit[a] += qf[i] * bf2f(a8[i]);
        }
    }
    float m = -3.0e38f;
#pragma unroll
    for (int a = 0; a < 32; ++a) m = fmaxf(m, logit[a]);
    float e[32], sum = 0.f;
#pragma unroll
    for (int a = 0; a < 32; ++a) { e[a] = __expf(logit[a] - m); sum += e[a]; }
    float inv = 1.0f / sum;
#pragma unroll
    for (int v = 0; v < 4; ++v) {
        u16x8 o;
#pragma unroll
        for (int i = 0; i < 8; ++i) o[i] = f2bf(e[v * 8 + i] * inv);
        *(u16x8*)(Qattn + (size_t)tok * 256 + h * 32 + v * 8) = o;
    }
}

// ------------------------------- k_out -----------------------------------------
// out[tok][j] = (Qattn[tok] @ AVPt[b]) * (mask>0), f32.
// BM=128, BN=128, BK=32, K=256. grid (4 n-tiles, 512 m-tiles), block 256
__global__ __launch_bounds__(256) void k_out(const unsigned short* __restrict__ Qattn,
                                             const unsigned short* __restrict__ AVPt,
                                             const int* __restrict__ mask,
                                             float* __restrict__ out) {
    __shared__ __align__(16) unsigned char Asm[128 * 64];
    __shared__ __align__(16) unsigned char Bsm[128 * 64];
    const int tid = threadIdx.x, l = tid & 63, wid = tid >> 6;
    const int wm = wid >> 1, wn = wid & 1;
    const int nt = blockIdx.x, mt = blockIdx.y;
    const int m0 = mt * 128, j0 = nt * 128;
    const int b = m0 >> 14;
    const int g = l >> 4, lr = l & 15;
    f32x4 acc[4][4] = {};

    for (int ks = 0; ks < 8; ++ks) {
#pragma unroll
        for (int j = 0; j < 2; ++j) {
            int i = tid + 256 * j;
            int row = i >> 2, c = i & 3;
            int lof = row * 64 + ((c ^ (row & 3)) << 4);
            *(u16x8*)(Asm + lof) = *(const u16x8*)(Qattn + (size_t)(m0 + row) * 256 + ks * 32 + c * 8);
            *(u16x8*)(Bsm + lof) = *(const u16x8*)(AVPt + (size_t)b * 131072 + (size_t)(j0 + row) * 256 + ks * 32 + c * 8);
        }
        __syncthreads();
        bf16x8 af[4], bfr[4];
#pragma unroll
        for (int f = 0; f < 4; ++f) {
            int ra = wm * 64 + f * 16 + lr;
            af[f] = *(const bf16x8*)(Asm + ra * 64 + ((g ^ (ra & 3)) << 4));
            int rb = wn * 64 + f * 16 + lr;
            bfr[f] = *(const bf16x8*)(Bsm + rb * 64 + ((g ^ (rb & 3)) << 4));
        }
#pragma unroll
        for (int mf = 0; mf < 4; ++mf)
#pragma unroll
            for (int nf = 0; nf < 4; ++nf)
                acc[mf][nf] = MFMA16(af[mf], bfr[nf], acc[mf][nf]);
        __syncthreads();
    }
#pragma unroll
    for (int mf = 0; mf < 4; ++mf) {
        int trow = m0 + wm * 64 + mf * 16 + g * 4;
#pragma unroll
        for (int r = 0; r < 4; ++r) {
            float mv = (mask[trow + r] > 0) ? 1.0f : 0.0f;
#pragma unroll
            for (int nf = 0; nf < 4; ++nf) {
                int j = j0 + wn * 64 + nf * 16 + lr;
                out[(size_t)(trow + r) * 512 + j] = acc[mf][nf][r] * mv;
            }
        }
    }
}

// ------------------------------- launch -----------------------------------------
extern "C" void kernel_launch(void* const* d_in, const int* in_sizes, int n_in,
                              void* d_out, int out_size, void* d_ws, size_t ws_size,
                              hipStream_t stream) {
    const float* x  = (const float*)d_in[0];
    const int*  mk  = (const int*)d_in[1];
    const float* at = (const float*)d_in[2];
    const float* Wq = (const float*)d_in[3];
    const float* Wk = (const float*)d_in[4];
    const float* Wv = (const float*)d_in[5];
    const float* Wp = (const float*)d_in[6];
    float* out = (float*)d_out;
    char* ws = (char*)d_ws;

    unsigned short* xbf   = (unsigned short*)(ws);                       // 64 MiB
    unsigned short* Kbf   = (unsigned short*)(ws + ((size_t)64 << 20));  // 64 MiB
    unsigned short* Vt    = (unsigned short*)(ws + ((size_t)128 << 20)); // 64 MiB
    unsigned short* Qbf   = (unsigned short*)(ws + ((size_t)192 << 20)); // 64 MiB
    unsigned short* Wt    = (unsigned short*)(ws + ((size_t)256 << 20)); // 2 MiB (4 mats)
    unsigned short* abf   = (unsigned short*)(ws + ((size_t)258 << 20)); // 32 KiB
    unsigned short* avbf  = (unsigned short*)(ws + ((size_t)259 << 20)); // 128 KiB
    unsigned short* AVPt  = (unsigned short*)(ws + ((size_t)260 << 20)); // 1 MiB
    unsigned short* Qattn = xbf;  // alias: xbf is dead after k_qkv

    k_cvt_x<<<16384, 256, 0, stream>>>(x, xbf);
    k_w_t<<<dim3(16, 16, 4), 256, 0, stream>>>(Wq, Wk, Wv, Wp, Wt);
    k_pack_a<<<64, 256, 0, stream>>>(at, abf);
    k_qkv<<<dim3(8, 512), 256, 0, stream>>>(xbf, Wt, Wt + 262144, Wt + 524288,
                                            Qbf, Kbf, Vt);
    k_agent<<<32, 512, 0, stream>>>(Kbf, Vt, abf, mk, avbf);
    k_avp<<<32, 64, 0, stream>>>(avbf, Wt + 786432, AVPt);
    k_qattn<<<2048, 256, 0, stream>>>(Qbf, abf, Qattn);
    k_out<<<dim3(4, 512), 256, 0, stream>>>(Qattn, AVPt, mk, out);
}

// Round 2
// 363.652 us; speedup vs baseline: 1.6487x; 1.6487x over previous
//
#include <hip/hip_runtime.h>

// ---------------------------------------------------------------------------
// MaskedSuperAttention (agent attention), B=4 N=16384 C=512 H=8 HD=64 NA=32
//   k_cvt_x      : x f32 -> xbf bf16
//   k_w_t        : W* f32 [k][n] -> Wt bf16 [n][k]
//   k_pack_a     : agent_tokens -> abf [h][32][64] bf16
//   k_qkv        : Q,K (row layout), V (transposed [b][d][n]) = xbf @ W
//   k_agent_part : split-K flash: per (b,h,chunk of 256 tokens) ->
//                  partial (M[32], L[32], PV[32][64]) ; grid 2048
//   k_agent_comb : merge 64 partials per (b,h) -> agent_v bf16 ; grid 256
//   k_avp        : AVP[b,h] = agent_v @ Wproj slice -> AVPt [b][j][256] bf16
//   k_qattn      : MFMA softmax(q.a*scale) -> Qattn [tok][256] bf16
//   k_out        : out = (Qattn @ AVPt) * keymask
// ---------------------------------------------------------------------------

typedef float  f32x4   __attribute__((ext_vector_type(4)));
typedef short  bf16x8  __attribute__((ext_vector_type(8)));
typedef unsigned short u16x4 __attribute__((ext_vector_type(4)));
typedef unsigned short u16x8 __attribute__((ext_vector_type(8)));

#define MFMA16(a, b, c) __builtin_amdgcn_mfma_f32_16x16x32_bf16((a), (b), (c), 0, 0, 0)

__device__ __forceinline__ unsigned short f2bf(float f) {
    unsigned u = __builtin_bit_cast(unsigned, f);
    u += 0x7FFFu + ((u >> 16) & 1u);        // RTNE
    return (unsigned short)(u >> 16);
}
__device__ __forceinline__ float bf2f(unsigned short h) {
    unsigned u = ((unsigned)h) << 16;
    return __builtin_bit_cast(float, u);
}

// ------------------------------- k_cvt_x -----------------------------------
__global__ __launch_bounds__(256) void k_cvt_x(const float* __restrict__ x,
                                               unsigned short* __restrict__ xbf) {
    size_t i = ((size_t)blockIdx.x * 256 + threadIdx.x) * 8;
    float4 v0 = *(const float4*)(x + i);
    float4 v1 = *(const float4*)(x + i + 4);
    u16x8 o;
    o[0] = f2bf(v0.x); o[1] = f2bf(v0.y); o[2] = f2bf(v0.z); o[3] = f2bf(v0.w);
    o[4] = f2bf(v1.x); o[5] = f2bf(v1.y); o[6] = f2bf(v1.z); o[7] = f2bf(v1.w);
    *(u16x8*)(xbf + i) = o;
}

// ------------------------------- k_w_t --------------------------------------
__global__ __launch_bounds__(256) void k_w_t(const float* __restrict__ Wq,
                                             const float* __restrict__ Wk,
                                             const float* __restrict__ Wv,
                                             const float* __restrict__ Wp,
                                             unsigned short* __restrict__ Wt) {
    __shared__ float t[32][33];
    const int z = blockIdx.z;
    const float* src = (z == 0) ? Wq : (z == 1) ? Wk : (z == 2) ? Wv : Wp;
    unsigned short* dst = Wt + (size_t)z * 262144;
    const int k0 = blockIdx.y * 32, n0 = blockIdx.x * 32;
#pragma unroll
    for (int j = 0; j < 4; ++j) {
        int i = threadIdx.x + 256 * j;
        int ky = i >> 5, nx = i & 31;
        t[ky][nx] = src[(size_t)(k0 + ky) * 512 + n0 + nx];
    }
    __syncthreads();
#pragma unroll
    for (int j = 0; j < 4; ++j) {
        int i = threadIdx.x + 256 * j;
        int ny = i >> 5, kx = i & 31;
        dst[(size_t)(n0 + ny) * 512 + k0 + kx] = f2bf(t[kx][ny]);
    }
}

// ------------------------------- k_pack_a -----------------------------------
__global__ __launch_bounds__(256) void k_pack_a(const float* __restrict__ at,
                                                unsigned short* __restrict__ abf) {
    int idx = threadIdx.x + blockIdx.x * 256;       // 0..16383
    int h = idx >> 11, ag = (idx >> 6) & 31, d = idx & 63;
    abf[idx] = f2bf(at[ag * 512 + h * 64 + d]);
}

// ------------------------------- k_qkv ---------------------------------------
__global__ __launch_bounds__(256) void k_qkv(const unsigned short* __restrict__ xbf,
                                             const unsigned short* __restrict__ Wqt,
                                             const unsigned short* __restrict__ Wkt,
                                             const unsigned short* __restrict__ Wvt,
                                             unsigned short* __restrict__ Qbf,
                                             unsigned short* __restrict__ Kbf,
                                             unsigned short* __restrict__ Vt) {
    __shared__ __align__(16) unsigned char Asm[128 * 64];
    __shared__ __align__(16) unsigned char Bsm[3][64 * 64];
    const int tid = threadIdx.x;
    const int l = tid & 63, wid = tid >> 6;
    const int nt = blockIdx.x, mt = blockIdx.y;
    const int m0 = mt * 128, n0 = nt * 64;
    const int g = l >> 4, lr = l & 15;

    f32x4 acc[3][2][4] = {};

    for (int ks = 0; ks < 16; ++ks) {
#pragma unroll
        for (int j = 0; j < 2; ++j) {
            int i = tid + 256 * j;
            int row = i >> 2, c = i & 3;
            u16x8 v = *(const u16x8*)(xbf + (size_t)(m0 + row) * 512 + ks * 32 + c * 8);
            *(u16x8*)(Asm + row * 64 + ((c ^ (row & 3)) << 4)) = v;
        }
        {
            int row = tid >> 2, c = tid & 3;
            size_t gof = (size_t)(n0 + row) * 512 + ks * 32 + c * 8;
            int lof = row * 64 + ((c ^ (row & 3)) << 4);
            *(u16x8*)(Bsm[0] + lof) = *(const u16x8*)(Wqt + gof);
            *(u16x8*)(Bsm[1] + lof) = *(const u16x8*)(Wkt + gof);
            *(u16x8*)(Bsm[2] + lof) = *(const u16x8*)(Wvt + gof);
        }
        __syncthreads();
        bf16x8 af[2];
#pragma unroll
        for (int mf = 0; mf < 2; ++mf) {
            int row = wid * 32 + mf * 16 + lr;
            af[mf] = *(const bf16x8*)(Asm + row * 64 + ((g ^ (row & 3)) << 4));
        }
#pragma unroll
        for (int mat = 0; mat < 3; ++mat) {
#pragma unroll
            for (int nf = 0; nf < 4; ++nf) {
                int row = nf * 16 + lr;
                bf16x8 bfr = *(const bf16x8*)(Bsm[mat] + row * 64 + ((g ^ (row & 3)) << 4));
#pragma unroll
                for (int mf = 0; mf < 2; ++mf)
                    acc[mat][mf][nf] = MFMA16(af[mf], bfr, acc[mat][mf][nf]);
            }
        }
        __syncthreads();
    }

    const int b = m0 >> 14;
    const int nloc0 = m0 & 16383;
#pragma unroll
    for (int mf = 0; mf < 2; ++mf) {
#pragma unroll
        for (int nf = 0; nf < 4; ++nf) {
            int trow = wid * 32 + mf * 16 + g * 4;
            int d = n0 + nf * 16 + lr;
#pragma unroll
            for (int r = 0; r < 4; ++r) {
                size_t o = (size_t)(m0 + trow + r) * 512 + d;
                Qbf[o] = f2bf(acc[0][mf][nf][r]);
                Kbf[o] = f2bf(acc[1][mf][nf][r]);
            }
            u16x4 vv;
            vv[0] = f2bf(acc[2][mf][nf][0]); vv[1] = f2bf(acc[2][mf][nf][1]);
            vv[2] = f2bf(acc[2][mf][nf][2]); vv[3] = f2bf(acc[2][mf][nf][3]);
            *(u16x4*)(Vt + ((size_t)(b * 512 + d)) * 16384 + nloc0 + trow) = vv;
        }
    }
}

// ------------------------------- k_agent_part --------------------------------
// grid (64 chunks, 32 bh), block 256 (4 waves x 64 tokens).
// Scores computed ONCE, kept in regs. Outputs per block: M[32], L[32],
// PV[32][64] f32 (unnormalized, relative to block M).
__global__ __launch_bounds__(256) void k_agent_part(const unsigned short* __restrict__ Kbf,
                                                    const unsigned short* __restrict__ Vt,
                                                    const unsigned short* __restrict__ abf,
                                                    const int* __restrict__ mask,
                                                    float* __restrict__ part_pv,
                                                    float* __restrict__ part_ml) {
    __shared__ __align__(16) unsigned char Psm[4][2048];
    __shared__ float avs[4][2048];
    __shared__ float redM[4][32];
    __shared__ float redL[4][32];
    const int tid = threadIdx.x, l = tid & 63, wid = tid >> 6;
    const int g = l >> 4, lr = l & 15;
    const int c = blockIdx.x, bh = blockIdx.y, b = bh >> 3, h = bh & 7;
    const int tok0 = c * 256 + wid * 64;

    // hoisted agent A-fragments
    bf16x8 af[2][2];
#pragma unroll
    for (int mf = 0; mf < 2; ++mf)
#pragma unroll
        for (int ks = 0; ks < 2; ++ks)
            af[mf][ks] = *(const bf16x8*)(abf + (size_t)h * 2048 + (mf * 16 + lr) * 64 + ks * 32 + g * 8);

    const size_t kbase = (size_t)(b * 16384) * 512 + h * 64;
    const int maskbase = b * 16384;

    // ---- scores for this wave's 64 tokens (kept in registers) ----
    f32x4 sc[4][2];
#pragma unroll
    for (int it = 0; it < 4; ++it) {
        int tokn = tok0 + it * 16 + lr;
        const unsigned short* kp = Kbf + kbase + (size_t)tokn * 512;
        bf16x8 b0 = *(const bf16x8*)(kp + g * 8);
        bf16x8 b1 = *(const bf16x8*)(kp + 32 + g * 8);
        int mv = mask[maskbase + tokn];
        f32x4 z = {0.f, 0.f, 0.f, 0.f};
        f32x4 a0 = MFMA16(af[0][0], b0, z); a0 = MFMA16(af[0][1], b1, a0);
        f32x4 a1 = MFMA16(af[1][0], b0, z); a1 = MFMA16(af[1][1], b1, a1);
#pragma unroll
        for (int r = 0; r < 4; ++r) {
            a0[r] = (mv > 0) ? a0[r] * 0.125f : -1.0e9f;
            a1[r] = (mv > 0) ? a1[r] * 0.125f : -1.0e9f;
        }
        sc[it][0] = a0; sc[it][1] = a1;
    }

    // ---- block max per agent ----
    float mx[8];
#pragma unroll
    for (int s = 0; s < 8; ++s) {
        float m = sc[0][s >> 2][s & 3];
        m = fmaxf(m, sc[1][s >> 2][s & 3]);
        m = fmaxf(m, sc[2][s >> 2][s & 3]);
        m = fmaxf(m, sc[3][s >> 2][s & 3]);
#pragma unroll
        for (int k = 1; k < 16; k <<= 1) m = fmaxf(m, __shfl_xor(m, k));
        mx[s] = m;
    }
    if (lr == 0) {
#pragma unroll
        for (int s = 0; s < 8; ++s) {
            int ag = (s >> 2) * 16 + g * 4 + (s & 3);
            redM[wid][ag] = mx[s];
        }
    }
    __syncthreads();
    float M[8];
#pragma unroll
    for (int s = 0; s < 8; ++s) {
        int ag = (s >> 2) * 16 + g * 4 + (s & 3);
        M[s] = fmaxf(fmaxf(redM[0][ag], redM[1][ag]), fmaxf(redM[2][ag], redM[3][ag]));
    }

    // ---- P = exp(s - M), sumexp, PV ----
    float le[8] = {0.f, 0.f, 0.f, 0.f, 0.f, 0.f, 0.f, 0.f};
    f32x4 pv[2][4] = {};
    unsigned char* Pw = &Psm[wid][0];
    const size_t vbase = ((size_t)b * 512 + h * 64) * 16384;
#pragma unroll
    for (int it2 = 0; it2 < 2; ++it2) {
#pragma unroll
        for (int half = 0; half < 2; ++half) {
            int it = it2 * 2 + half;
            int tk = half * 16 + lr;
#pragma unroll
            for (int s = 0; s < 8; ++s) {
                float p = __expf(sc[it][s >> 2][s & 3] - M[s]);
                le[s] += p;
                int ag = (s >> 2) * 16 + g * 4 + (s & 3);
                *(unsigned short*)(Pw + ag * 64 + ((2 * tk) ^ (((ag >> 2) & 3) << 4))) = f2bf(p);
            }
        }
        int n0w = tok0 + it2 * 32;
        bf16x8 pa[2];
#pragma unroll
        for (int mf = 0; mf < 2; ++mf) {
            int ag = mf * 16 + lr;
            pa[mf] = *(const bf16x8*)(Pw + ag * 64 + ((g * 16) ^ (((ag >> 2) & 3) << 4)));
        }
#pragma unroll
        for (int nf = 0; nf < 4; ++nf) {
            int d = nf * 16 + lr;
            bf16x8 bv = *(const bf16x8*)(Vt + vbase + (size_t)d * 16384 + n0w + g * 8);
#pragma unroll
            for (int mf = 0; mf < 2; ++mf)
                pv[mf][nf] = MFMA16(pa[mf], bv, pv[mf][nf]);
        }
    }

    // ---- L reduce (within wave, then cross-wave via LDS) ----
#pragma unroll
    for (int s = 0; s < 8; ++s) {
#pragma unroll
        for (int k = 1; k < 16; k <<= 1) le[s] += __shfl_xor(le[s], k);
    }
    if (lr == 0) {
#pragma unroll
        for (int s = 0; s < 8; ++s) {
            int ag = (s >> 2) * 16 + g * 4 + (s & 3);
            redL[wid][ag] = le[s];
        }
    }

    // ---- cross-wave PV reduce ----
#pragma unroll
    for (int mf = 0; mf < 2; ++mf)
#pragma unroll
        for (int nf = 0; nf < 4; ++nf)
#pragma unroll
            for (int r = 0; r < 4; ++r) {
                int ag = mf * 16 + g * 4 + r;
                int d = nf * 16 + lr;
                avs[wid][ag * 64 + d] = pv[mf][nf][r];
            }
    __syncthreads();

    float* pout = part_pv + ((size_t)bh * 64 + c) * 2048;
#pragma unroll
    for (int j = 0; j < 8; ++j) {
        int idx = tid + 256 * j;
        pout[idx] = avs[0][idx] + avs[1][idx] + avs[2][idx] + avs[3][idx];
    }
    if (wid == 0 && lr == 0) {
#pragma unroll
        for (int s = 0; s < 8; ++s) {
            int ag = (s >> 2) * 16 + g * 4 + (s & 3);
            float L = redL[0][ag] + redL[1][ag] + redL[2][ag] + redL[3][ag];
            size_t o = ((size_t)bh * 64 + c) * 64 + ag * 2;
            part_ml[o] = M[s];
            part_ml[o + 1] = L;
        }
    }
}

// ------------------------------- k_agent_comb --------------------------------
// grid (8 agent-groups, 32 bh), block 256. Each block: 4 agents x 64 dims.
__global__ __launch_bounds__(256) void k_agent_comb(const float* __restrict__ part_pv,
                                                    const float* __restrict__ part_ml,
                                                    unsigned short* __restrict__ avbf) {
    __shared__ float scl[64][4];
    __shared__ float iLg[4], Mg[4];
    const int tid = threadIdx.x;
    const int ag0 = blockIdx.x * 4, bh = blockIdx.y;
    if (tid < 4) {
        int ag = ag0 + tid;
        const float* ml = part_ml + (size_t)bh * 4096 + ag * 2;
        float M = -3.0e38f;
#pragma unroll 4
        for (int c = 0; c < 64; ++c) M = fmaxf(M, ml[c * 64]);
        float L = 0.f;
#pragma unroll 4
        for (int c = 0; c < 64; ++c) L += __expf(ml[c * 64] - M) * ml[c * 64 + 1];
        Mg[tid] = M; iLg[tid] = 1.0f / L;
    }
    __syncthreads();
    {
        int c = tid >> 2, agl = tid & 3;
        scl[c][agl] = __expf(part_ml[(size_t)bh * 4096 + (size_t)c * 64 + (ag0 + agl) * 2] - Mg[agl]);
    }
    __syncthreads();
    const int agl = tid >> 6, d = tid & 63;
    const float* pv = part_pv + (size_t)bh * 64 * 2048 + (size_t)(ag0 + agl) * 64 + d;
    float acc = 0.f;
#pragma unroll 4
    for (int c = 0; c < 64; ++c) acc += scl[c][agl] * pv[(size_t)c * 2048];
    avbf[(size_t)bh * 2048 + (size_t)(ag0 + agl) * 64 + d] = f2bf(acc * iLg[agl]);
}

// ------------------------------- k_avp ----------------------------------------
__global__ __launch_bounds__(64) void k_avp(const unsigned short* __restrict__ avbf,
                                            const unsigned short* __restrict__ Wpt,
                                            unsigned short* __restrict__ AVPt) {
    const int l = threadIdx.x & 63;
    const int bh = blockIdx.x, b = bh >> 3, h = bh & 7;
    const int g = l >> 4, lr = l & 15;
    bf16x8 avf[2][2];
#pragma unroll
    for (int mf = 0; mf < 2; ++mf)
#pragma unroll
        for (int ks = 0; ks < 2; ++ks)
            avf[mf][ks] = *(const bf16x8*)(avbf + (size_t)bh * 2048 + (mf * 16 + lr) * 64 + ks * 32 + g * 8);
#pragma unroll 4
    for (int nf = 0; nf < 32; ++nf) {
        int j = nf * 16 + lr;
        bf16x8 w0 = *(const bf16x8*)(Wpt + (size_t)j * 512 + h * 64 + g * 8);
        bf16x8 w1 = *(const bf16x8*)(Wpt + (size_t)j * 512 + h * 64 + 32 + g * 8);
#pragma unroll
        for (int mf = 0; mf < 2; ++mf) {
            f32x4 z = {0.f, 0.f, 0.f, 0.f};
            f32x4 acc = MFMA16(avf[mf][0], w0, z);
            acc = MFMA16(avf[mf][1], w1, acc);
            u16x4 o;
            o[0] = f2bf(acc[0]); o[1] = f2bf(acc[1]); o[2] = f2bf(acc[2]); o[3] = f2bf(acc[3]);
            *(u16x4*)(AVPt + (size_t)b * 131072 + (size_t)j * 256 + h * 32 + mf * 16 + g * 4) = o;
        }
    }
}

// ------------------------------- k_qattn ---------------------------------------
// MFMA version: grid 1024 (64 tokens each), block 256; wave w -> heads 2w,2w+1.
// Swapped operands: D rows = agents, cols = tokens; softmax over rows via
// per-lane 8 regs + shfl_xor(16), shfl_xor(32).
__global__ __launch_bounds__(256) void k_qattn(const unsigned short* __restrict__ Qbf,
                                               const unsigned short* __restrict__ abf,
                                               unsigned short* __restrict__ Qattn) {
    const int tid = threadIdx.x, l = tid & 63, wid = tid >> 6;
    const int g = l >> 4, lr = l & 15;
    const int tok0 = blockIdx.x * 64;
#pragma unroll
    for (int hh = 0; hh < 2; ++hh) {
        const int h = wid * 2 + hh;
        bf16x8 af[2][2];
#pragma unroll
        for (int mf = 0; mf < 2; ++mf)
#pragma unroll
            for (int ks = 0; ks < 2; ++ks)
                af[mf][ks] = *(const bf16x8*)(abf + (size_t)h * 2048 + (mf * 16 + lr) * 64 + ks * 32 + g * 8);
        f32x4 acc[2][4] = {};
#pragma unroll
        for (int nf = 0; nf < 4; ++nf) {
            int tokn = tok0 + nf * 16 + lr;
            const unsigned short* qp = Qbf + (size_t)tokn * 512 + h * 64;
            bf16x8 q0 = *(const bf16x8*)(qp + g * 8);
            bf16x8 q1 = *(const bf16x8*)(qp + 32 + g * 8);
#pragma unroll
            for (int mf = 0; mf < 2; ++mf) {
                acc[mf][nf] = MFMA16(af[mf][0], q0, acc[mf][nf]);
                acc[mf][nf] = MFMA16(af[mf][1], q1, acc[mf][nf]);
            }
        }
#pragma unroll
        for (int nf = 0; nf < 4; ++nf) {
            float mt = -3.0e38f;
#pragma unroll
            for (int s = 0; s < 8; ++s) mt = fmaxf(mt, acc[s >> 2][nf][s & 3] * 0.125f);
            mt = fmaxf(mt, __shfl_xor(mt, 16));
            mt = fmaxf(mt, __shfl_xor(mt, 32));
            float e[8], sum = 0.f;
#pragma unroll
            for (int s = 0; s < 8; ++s) {
                e[s] = __expf(acc[s >> 2][nf][s & 3] * 0.125f - mt);
                sum += e[s];
            }
            sum += __shfl_xor(sum, 16);
            sum += __shfl_xor(sum, 32);
            float inv = 1.0f / sum;
            int tokn = tok0 + nf * 16 + lr;
#pragma unroll
            for (int mf = 0; mf < 2; ++mf) {
                u16x4 o;
#pragma unroll
                for (int r = 0; r < 4; ++r) o[r] = f2bf(e[mf * 4 + r] * inv);
                *(u16x4*)(Qattn + (size_t)tokn * 256 + h * 32 + mf * 16 + g * 4) = o;
            }
        }
    }
}

// ------------------------------- k_out -----------------------------------------
__global__ __launch_bounds__(256) void k_out(const unsigned short* __restrict__ Qattn,
                                             const unsigned short* __restrict__ AVPt,
                                             const int* __restrict__ mask,
                                             float* __restrict__ out) {
    __shared__ __align__(16) unsigned char Asm[128 * 64];
    __shared__ __align__(16) unsigned char Bsm[128 * 64];
    const int tid = threadIdx.x, l = tid & 63, wid = tid >> 6;
    const int wm = wid >> 1, wn = wid & 1;
    const int nt = blockIdx.x, mt = blockIdx.y;
    const int m0 = mt * 128, j0 = nt * 128;
    const int b = m0 >> 14;
    const int g = l >> 4, lr = l & 15;
    f32x4 acc[4][4] = {};

    for (int ks = 0; ks < 8; ++ks) {
#pragma unroll
        for (int j = 0; j < 2; ++j) {
            int i = tid + 256 * j;
            int row = i >> 2, c = i & 3;
            int lof = row * 64 + ((c ^ (row & 3)) << 4);
            *(u16x8*)(Asm + lof) = *(const u16x8*)(Qattn + (size_t)(m0 + row) * 256 + ks * 32 + c * 8);
            *(u16x8*)(Bsm + lof) = *(const u16x8*)(AVPt + (size_t)b * 131072 + (size_t)(j0 + row) * 256 + ks * 32 + c * 8);
        }
        __syncthreads();
        bf16x8 af[4], bfr[4];
#pragma unroll
        for (int f = 0; f < 4; ++f) {
            int ra = wm * 64 + f * 16 + lr;
            af[f] = *(const bf16x8*)(Asm + ra * 64 + ((g ^ (ra & 3)) << 4));
            int rb = wn * 64 + f * 16 + lr;
            bfr[f] = *(const bf16x8*)(Bsm + rb * 64 + ((g ^ (rb & 3)) << 4));
        }
#pragma unroll
        for (int mf = 0; mf < 4; ++mf)
#pragma unroll
            for (int nf = 0; nf < 4; ++nf)
                acc[mf][nf] = MFMA16(af[mf], bfr[nf], acc[mf][nf]);
        __syncthreads();
    }
#pragma unroll
    for (int mf = 0; mf < 4; ++mf) {
        int trow = m0 + wm * 64 + mf * 16 + g * 4;
#pragma unroll
        for (int r = 0; r < 4; ++r) {
            float mv = (mask[trow + r] > 0) ? 1.0f : 0.0f;
#pragma unroll
            for (int nf = 0; nf < 4; ++nf) {
                int j = j0 + wn * 64 + nf * 16 + lr;
                out[(size_t)(trow + r) * 512 + j] = acc[mf][nf][r] * mv;
            }
        }
    }
}

// ------------------------------- launch -----------------------------------------
extern "C" void kernel_launch(void* const* d_in, const int* in_sizes, int n_in,
                              void* d_out, int out_size, void* d_ws, size_t ws_size,
                              hipStream_t stream) {
    const float* x  = (const float*)d_in[0];
    const int*  mk  = (const int*)d_in[1];
    const float* at = (const float*)d_in[2];
    const float* Wq = (const float*)d_in[3];
    const float* Wk = (const float*)d_in[4];
    const float* Wv = (const float*)d_in[5];
    const float* Wp = (const float*)d_in[6];
    float* out = (float*)d_out;
    char* ws = (char*)d_ws;

    unsigned short* xbf   = (unsigned short*)(ws);                       // 64 MiB (dead after k_qkv)
    unsigned short* Kbf   = (unsigned short*)(ws + ((size_t)64 << 20));  // 64 MiB
    unsigned short* Vt    = (unsigned short*)(ws + ((size_t)128 << 20)); // 64 MiB
    unsigned short* Qbf   = (unsigned short*)(ws + ((size_t)192 << 20)); // 64 MiB
    unsigned short* Wt    = (unsigned short*)(ws + ((size_t)256 << 20)); // 2 MiB
    unsigned short* abf   = (unsigned short*)(ws + ((size_t)258 << 20)); // 32 KiB
    unsigned short* avbf  = (unsigned short*)(ws + ((size_t)259 << 20)); // 128 KiB
    unsigned short* AVPt  = (unsigned short*)(ws + ((size_t)260 << 20)); // 1 MiB
    // partials live in the upper half of the (dead) xbf region:
    float* part_pv = (float*)(ws + ((size_t)32 << 20));                  // 16.8 MiB
    float* part_ml = (float*)(ws + ((size_t)52 << 20));                  // 0.5 MiB
    unsigned short* Qattn = xbf;  // lower 32 MiB of xbf region

    k_cvt_x<<<16384, 256, 0, stream>>>(x, xbf);
    k_w_t<<<dim3(16, 16, 4), 256, 0, stream>>>(Wq, Wk, Wv, Wp, Wt);
    k_pack_a<<<64, 256, 0, stream>>>(at, abf);
    k_qkv<<<dim3(8, 512), 256, 0, stream>>>(xbf, Wt, Wt + 262144, Wt + 524288,
                                            Qbf, Kbf, Vt);
    k_agent_part<<<dim3(64, 32), 256, 0, stream>>>(Kbf, Vt, abf, mk, part_pv, part_ml);
    k_agent_comb<<<dim3(8, 32), 256, 0, stream>>>(part_pv, part_ml, avbf);
    k_avp<<<32, 64, 0, stream>>>(avbf, Wt + 786432, AVPt);
    k_qattn<<<1024, 256, 0, stream>>>(Qbf, abf, Qattn);
    k_out<<<dim3(4, 512), 256, 0, stream>>>(Qattn, AVPt, mk, out);
}

// Round 4
// 302.646 us; speedup vs baseline: 1.9811x; 1.2016x over previous
//
#include <hip/hip_runtime.h>

// ---------------------------------------------------------------------------
// MaskedSuperAttention (agent attention), B=4 N=16384 C=512 H=8 HD=64 NA=32
//   k_cvt_x      : x f32 -> xt bf16, TILED (128x64 tiles, XOR-swizzled rows)
//   k_w_t        : W* f32 [k][n] -> Wt bf16 [n][k] row-major (for k_avp)
//   k_w_tile     : Wq/Wk/Wv -> wtl tiled-swizzled (for k_qkv gload_lds)
//   k_pack_a     : agent_tokens -> abf [h][32][64] bf16
//   k_qkv        : Q,K (row), V (transposed) = x @ W ; global_load_lds staging
//   k_agent_part : split-K flash partials ; grid 2048
//   k_agent_comb : merge partials -> agent_v bf16
//   k_avp        : AVP = agent_v @ Wproj -> AVPt TILED
//   k_qattn      : MFMA softmax(q.a*scale) -> Qattn TILED
//   k_out        : out = (Qattn @ AVPt) * keymask ; global_load_lds staging
// Tiled layout: tile = 128 rows x 64 k (16 KiB); byte(row,c8) =
//   base + row*128 + ((c8 ^ (row&7))<<4)   (c8 = 16B slot, 0..7)
// R4 fix: R3 had wtl [258,259.5MiB) overlapping abf @259MiB -> k_pack_a
// clobbered weight tiles 128..131 (head-5 Q/K/V cols) -> absmax 6.9e-3.
// abf/avbf moved above 259.5 MiB. No other changes.
// ---------------------------------------------------------------------------

typedef float  f32x4   __attribute__((ext_vector_type(4)));
typedef short  bf16x8  __attribute__((ext_vector_type(8)));
typedef unsigned short u16x4 __attribute__((ext_vector_type(4)));
typedef unsigned short u16x8 __attribute__((ext_vector_type(8)));

#define MFMA16(a, b, c) __builtin_amdgcn_mfma_f32_16x16x32_bf16((a), (b), (c), 0, 0, 0)

__device__ __forceinline__ unsigned short f2bf(float f) {
    unsigned u = __builtin_bit_cast(unsigned, f);
    u += 0x7FFFu + ((u >> 16) & 1u);        // RTNE
    return (unsigned short)(u >> 16);
}
__device__ __forceinline__ float bf2f(unsigned short h) {
    unsigned u = ((unsigned)h) << 16;
    return __builtin_bit_cast(float, u);
}
__device__ __forceinline__ void gl2lds16(const void* g, void* l) {
    __builtin_amdgcn_global_load_lds(
        (const __attribute__((address_space(1))) unsigned int*)g,
        (__attribute__((address_space(3))) unsigned int*)l, 16, 0, 0);
}

// ------------------------------- k_cvt_x -----------------------------------
// x f32 [tok][512] -> xt tiled: tile t = mt*8+ks (mt=tok>>7, ks of 64 k),
// 16 KiB each, swizzled. grid 16384, block 256.
__global__ __launch_bounds__(256) void k_cvt_x(const float* __restrict__ x,
                                               unsigned char* __restrict__ xt) {
    int v = blockIdx.x * 256 + threadIdx.x;
    int tile = v >> 10;             // 0..4095
    int q = v & 1023;
    int row = q >> 3, c = q & 7;
    int mt = tile >> 3, ks = tile & 7;
    const float* sp = x + ((size_t)(mt * 128 + row)) * 512 + ks * 64 + c * 8;
    float4 v0 = *(const float4*)sp;
    float4 v1 = *(const float4*)(sp + 4);
    u16x8 o;
    o[0] = f2bf(v0.x); o[1] = f2bf(v0.y); o[2] = f2bf(v0.z); o[3] = f2bf(v0.w);
    o[4] = f2bf(v1.x); o[5] = f2bf(v1.y); o[6] = f2bf(v1.z); o[7] = f2bf(v1.w);
    *(u16x8*)(xt + (size_t)tile * 16384 + row * 128 + ((c ^ (row & 7)) << 4)) = o;
}

// ------------------------------- k_w_t --------------------------------------
// row-major transposed weights (k_avp needs Wproj^T). grid (16,16,4), block 256
__global__ __launch_bounds__(256) void k_w_t(const float* __restrict__ Wq,
                                             const float* __restrict__ Wk,
                                             const float* __restrict__ Wv,
                                             const float* __restrict__ Wp,
                                             unsigned short* __restrict__ Wt) {
    __shared__ float t[32][33];
    const int z = blockIdx.z;
    const float* src = (z == 0) ? Wq : (z == 1) ? Wk : (z == 2) ? Wv : Wp;
    unsigned short* dst = Wt + (size_t)z * 262144;
    const int k0 = blockIdx.y * 32, n0 = blockIdx.x * 32;
#pragma unroll
    for (int j = 0; j < 4; ++j) {
        int i = threadIdx.x + 256 * j;
        int ky = i >> 5, nx = i & 31;
        t[ky][nx] = src[(size_t)(k0 + ky) * 512 + n0 + nx];
    }
    __syncthreads();
#pragma unroll
    for (int j = 0; j < 4; ++j) {
        int i = threadIdx.x + 256 * j;
        int ny = i >> 5, kx = i & 31;
        dst[(size_t)(n0 + ny) * 512 + k0 + kx] = f2bf(t[kx][ny]);
    }
}

// ------------------------------- k_w_tile -----------------------------------
// Wq/Wk/Wv -> tiled-swizzled wtl: trio tile (nt,ks,mat) of [64 n][64 k], 8 KiB.
// grid (8 ks, 8 nt, 3 mat), block 256.
__global__ __launch_bounds__(256) void k_w_tile(const float* __restrict__ Wq,
                                                const float* __restrict__ Wk,
                                                const float* __restrict__ Wv,
                                                unsigned char* __restrict__ wtl) {
    const int ks = blockIdx.x, nt = blockIdx.y, mat = blockIdx.z;
    const float* src = (mat == 0) ? Wq : (mat == 1) ? Wk : Wv;
    const size_t dbase = ((size_t)((nt * 8 + ks) * 3 + mat)) * 8192;
    const int row = threadIdx.x & 63;
#pragma unroll
    for (int cc = 0; cc < 2; ++cc) {
        int c = (threadIdx.x >> 6) + cc * 4;
        u16x8 o;
#pragma unroll
        for (int j = 0; j < 8; ++j)
            o[j] = f2bf(src[(size_t)(ks * 64 + c * 8 + j) * 512 + nt * 64 + row]);
        *(u16x8*)(wtl + dbase + row * 128 + ((c ^ (row & 7)) << 4)) = o;
    }
}

// ------------------------------- k_pack_a -----------------------------------
__global__ __launch_bounds__(256) void k_pack_a(const float* __restrict__ at,
                                                unsigned short* __restrict__ abf) {
    int idx = threadIdx.x + blockIdx.x * 256;       // 0..16383
    int h = idx >> 11, ag = (idx >> 6) & 31, d = idx & 63;
    abf[idx] = f2bf(at[ag * 512 + h * 64 + d]);
}

// ------------------------------- k_qkv ---------------------------------------
// BM=128, BN=192 (3 mats x 64), BK=64. 4 waves 2x2, wave tile 64x96.
// grid 4096 (XCD-swizzled), block 256. gload_lds staging of pre-swizzled tiles.
__global__ __launch_bounds__(256) void k_qkv(const unsigned char* __restrict__ xt,
                                             const unsigned char* __restrict__ wtl,
                                             unsigned short* __restrict__ Qbf,
                                             unsigned short* __restrict__ Kbf,
                                             unsigned short* __restrict__ Vt) {
    __shared__ __align__(16) unsigned char As[16384];
    __shared__ __align__(16) unsigned char Bs[24576];
    const int tid = threadIdx.x, l = tid & 63, wid = tid >> 6;
    const int g = l >> 4, lr = l & 15;
    const int wm = wid >> 1, wn = wid & 1;
    const int d = blockIdx.x;
    const int nt = (d >> 3) & 7;
    const int mt = (d & 7) + ((d >> 6) << 3);
    const int m0 = mt * 128, n0 = nt * 64;

    f32x4 acc[4][6] = {};

    for (int ks = 0; ks < 8; ++ks) {
        const size_t abase = ((size_t)(mt * 8 + ks)) * 16384;
        const size_t bbase = ((size_t)((nt * 8 + ks) * 3)) * 8192;
#pragma unroll
        for (int i = 0; i < 4; ++i)
            gl2lds16(xt + abase + i * 4096 + tid * 16, As + i * 4096 + tid * 16);
#pragma unroll
        for (int i = 0; i < 6; ++i)
            gl2lds16(wtl + bbase + i * 4096 + tid * 16, Bs + i * 4096 + tid * 16);
        __syncthreads();

        bf16x8 af[4][2];
#pragma unroll
        for (int mf = 0; mf < 4; ++mf) {
            int row = wm * 64 + mf * 16 + lr;
#pragma unroll
            for (int k2 = 0; k2 < 2; ++k2)
                af[mf][k2] = *(const bf16x8*)(As + row * 128 + (((k2 * 4 + g) ^ (row & 7)) << 4));
        }
#pragma unroll
        for (int k2 = 0; k2 < 2; ++k2) {
#pragma unroll
            for (int nf = 0; nf < 6; ++nf) {
                int f = wn * 6 + nf, mat = f >> 2, sub = f & 3;
                int brow = sub * 16 + lr;
                bf16x8 bv = *(const bf16x8*)(Bs + mat * 8192 + brow * 128 +
                                             (((k2 * 4 + g) ^ (brow & 7)) << 4));
#pragma unroll
                for (int mf = 0; mf < 4; ++mf)
                    acc[mf][nf] = MFMA16(af[mf][k2], bv, acc[mf][nf]);
            }
        }
        __syncthreads();
    }

    const int b = m0 >> 14;
    const int nloc0 = m0 & 16383;
#pragma unroll
    for (int mf = 0; mf < 4; ++mf) {
        int trow = wm * 64 + mf * 16 + g * 4;
#pragma unroll
        for (int nf = 0; nf < 6; ++nf) {
            int f = wn * 6 + nf, mat = f >> 2, sub = f & 3;
            int dc = n0 + sub * 16 + lr;
            if (mat == 0) {
#pragma unroll
                for (int r = 0; r < 4; ++r)
                    Qbf[(size_t)(m0 + trow + r) * 512 + dc] = f2bf(acc[mf][nf][r]);
            } else if (mat == 1) {
#pragma unroll
                for (int r = 0; r < 4; ++r)
                    Kbf[(size_t)(m0 + trow + r) * 512 + dc] = f2bf(acc[mf][nf][r]);
            } else {
                u16x4 vv;
                vv[0] = f2bf(acc[mf][nf][0]); vv[1] = f2bf(acc[mf][nf][1]);
                vv[2] = f2bf(acc[mf][nf][2]); vv[3] = f2bf(acc[mf][nf][3]);
                *(u16x4*)(Vt + ((size_t)(b * 512 + dc)) * 16384 + nloc0 + trow) = vv;
            }
        }
    }
}

// ------------------------------- k_agent_part --------------------------------
// grid (64 chunks, 32 bh), block 256 (4 waves x 64 tokens).
__global__ __launch_bounds__(256) void k_agent_part(const unsigned short* __restrict__ Kbf,
                                                    const unsigned short* __restrict__ Vt,
                                                    const unsigned short* __restrict__ abf,
                                                    const int* __restrict__ mask,
                                                    float* __restrict__ part_pv,
                                                    float* __restrict__ part_ml) {
    __shared__ __align__(16) unsigned char Psm[4][2048];
    __shared__ float avs[4][2048];
    __shared__ float redM[4][32];
    __shared__ float redL[4][32];
    const int tid = threadIdx.x, l = tid & 63, wid = tid >> 6;
    const int g = l >> 4, lr = l & 15;
    const int c = blockIdx.x, bh = blockIdx.y, b = bh >> 3, h = bh & 7;
    const int tok0 = c * 256 + wid * 64;

    bf16x8 af[2][2];
#pragma unroll
    for (int mf = 0; mf < 2; ++mf)
#pragma unroll
        for (int ks = 0; ks < 2; ++ks)
            af[mf][ks] = *(const bf16x8*)(abf + (size_t)h * 2048 + (mf * 16 + lr) * 64 + ks * 32 + g * 8);

    const size_t kbase = (size_t)(b * 16384) * 512 + h * 64;
    const int maskbase = b * 16384;

    f32x4 sc[4][2];
#pragma unroll
    for (int it = 0; it < 4; ++it) {
        int tokn = tok0 + it * 16 + lr;
        const unsigned short* kp = Kbf + kbase + (size_t)tokn * 512;
        bf16x8 b0 = *(const bf16x8*)(kp + g * 8);
        bf16x8 b1 = *(const bf16x8*)(kp + 32 + g * 8);
        int mv = mask[maskbase + tokn];
        f32x4 z = {0.f, 0.f, 0.f, 0.f};
        f32x4 a0 = MFMA16(af[0][0], b0, z); a0 = MFMA16(af[0][1], b1, a0);
        f32x4 a1 = MFMA16(af[1][0], b0, z); a1 = MFMA16(af[1][1], b1, a1);
#pragma unroll
        for (int r = 0; r < 4; ++r) {
            a0[r] = (mv > 0) ? a0[r] * 0.125f : -1.0e9f;
            a1[r] = (mv > 0) ? a1[r] * 0.125f : -1.0e9f;
        }
        sc[it][0] = a0; sc[it][1] = a1;
    }

    float mx[8];
#pragma unroll
    for (int s = 0; s < 8; ++s) {
        float m = sc[0][s >> 2][s & 3];
        m = fmaxf(m, sc[1][s >> 2][s & 3]);
        m = fmaxf(m, sc[2][s >> 2][s & 3]);
        m = fmaxf(m, sc[3][s >> 2][s & 3]);
#pragma unroll
        for (int k = 1; k < 16; k <<= 1) m = fmaxf(m, __shfl_xor(m, k));
        mx[s] = m;
    }
    if (lr == 0) {
#pragma unroll
        for (int s = 0; s < 8; ++s) {
            int ag = (s >> 2) * 16 + g * 4 + (s & 3);
            redM[wid][ag] = mx[s];
        }
    }
    __syncthreads();
    float M[8];
#pragma unroll
    for (int s = 0; s < 8; ++s) {
        int ag = (s >> 2) * 16 + g * 4 + (s & 3);
        M[s] = fmaxf(fmaxf(redM[0][ag], redM[1][ag]), fmaxf(redM[2][ag], redM[3][ag]));
    }

    float le[8] = {0.f, 0.f, 0.f, 0.f, 0.f, 0.f, 0.f, 0.f};
    f32x4 pv[2][4] = {};
    unsigned char* Pw = &Psm[wid][0];
    const size_t vbase = ((size_t)b * 512 + h * 64) * 16384;
#pragma unroll
    for (int it2 = 0; it2 < 2; ++it2) {
#pragma unroll
        for (int half = 0; half < 2; ++half) {
            int it = it2 * 2 + half;
            int tk = half * 16 + lr;
#pragma unroll
            for (int s = 0; s < 8; ++s) {
                float p = __expf(sc[it][s >> 2][s & 3] - M[s]);
                le[s] += p;
                int ag = (s >> 2) * 16 + g * 4 + (s & 3);
                *(unsigned short*)(Pw + ag * 64 + ((2 * tk) ^ (((ag >> 2) & 3) << 4))) = f2bf(p);
            }
        }
        int n0w = tok0 + it2 * 32;
        bf16x8 pa[2];
#pragma unroll
        for (int mf = 0; mf < 2; ++mf) {
            int ag = mf * 16 + lr;
            pa[mf] = *(const bf16x8*)(Pw + ag * 64 + ((g * 16) ^ (((ag >> 2) & 3) << 4)));
        }
#pragma unroll
        for (int nf = 0; nf < 4; ++nf) {
            int dd = nf * 16 + lr;
            bf16x8 bv = *(const bf16x8*)(Vt + vbase + (size_t)dd * 16384 + n0w + g * 8);
#pragma unroll
            for (int mf = 0; mf < 2; ++mf)
                pv[mf][nf] = MFMA16(pa[mf], bv, pv[mf][nf]);
        }
    }

#pragma unroll
    for (int s = 0; s < 8; ++s) {
#pragma unroll
        for (int k = 1; k < 16; k <<= 1) le[s] += __shfl_xor(le[s], k);
    }
    if (lr == 0) {
#pragma unroll
        for (int s = 0; s < 8; ++s) {
            int ag = (s >> 2) * 16 + g * 4 + (s & 3);
            redL[wid][ag] = le[s];
        }
    }

#pragma unroll
    for (int mf = 0; mf < 2; ++mf)
#pragma unroll
        for (int nf = 0; nf < 4; ++nf)
#pragma unroll
            for (int r = 0; r < 4; ++r) {
                int ag = mf * 16 + g * 4 + r;
                int dd = nf * 16 + lr;
                avs[wid][ag * 64 + dd] = pv[mf][nf][r];
            }
    __syncthreads();

    float* pout = part_pv + ((size_t)bh * 64 + c) * 2048;
#pragma unroll
    for (int j = 0; j < 8; ++j) {
        int idx = tid + 256 * j;
        pout[idx] = avs[0][idx] + avs[1][idx] + avs[2][idx] + avs[3][idx];
    }
    if (wid == 0 && lr == 0) {
#pragma unroll
        for (int s = 0; s < 8; ++s) {
            int ag = (s >> 2) * 16 + g * 4 + (s & 3);
            float L = redL[0][ag] + redL[1][ag] + redL[2][ag] + redL[3][ag];
            size_t o = ((size_t)bh * 64 + c) * 64 + ag * 2;
            part_ml[o] = M[s];
            part_ml[o + 1] = L;
        }
    }
}

// ------------------------------- k_agent_comb --------------------------------
__global__ __launch_bounds__(256) void k_agent_comb(const float* __restrict__ part_pv,
                                                    const float* __restrict__ part_ml,
                                                    unsigned short* __restrict__ avbf) {
    __shared__ float scl[64][4];
    __shared__ float iLg[4], Mg[4];
    const int tid = threadIdx.x;
    const int ag0 = blockIdx.x * 4, bh = blockIdx.y;
    if (tid < 4) {
        int ag = ag0 + tid;
        const float* ml = part_ml + (size_t)bh * 4096 + ag * 2;
        float M = -3.0e38f;
#pragma unroll 4
        for (int c = 0; c < 64; ++c) M = fmaxf(M, ml[c * 64]);
        float L = 0.f;
#pragma unroll 4
        for (int c = 0; c < 64; ++c) L += __expf(ml[c * 64] - M) * ml[c * 64 + 1];
        Mg[tid] = M; iLg[tid] = 1.0f / L;
    }
    __syncthreads();
    {
        int c = tid >> 2, agl = tid & 3;
        scl[c][agl] = __expf(part_ml[(size_t)bh * 4096 + (size_t)c * 64 + (ag0 + agl) * 2] - Mg[agl]);
    }
    __syncthreads();
    const int agl = tid >> 6, dd = tid & 63;
    const float* pv = part_pv + (size_t)bh * 64 * 2048 + (size_t)(ag0 + agl) * 64 + dd;
    float acc = 0.f;
#pragma unroll 4
    for (int c = 0; c < 64; ++c) acc += scl[c][agl] * pv[(size_t)c * 2048];
    avbf[(size_t)bh * 2048 + (size_t)(ag0 + agl) * 64 + dd] = f2bf(acc * iLg[agl]);
}

// ------------------------------- k_avp ----------------------------------------
// AVP tiled write: tile ((b*4+jt)*4+kst) of [128 j][64 k] swizzled.
__global__ __launch_bounds__(64) void k_avp(const unsigned short* __restrict__ avbf,
                                            const unsigned short* __restrict__ Wpt,
                                            unsigned char* __restrict__ AVPt) {
    const int l = threadIdx.x & 63;
    const int bh = blockIdx.x, b = bh >> 3, h = bh & 7;
    const int g = l >> 4, lr = l & 15;
    bf16x8 avf[2][2];
#pragma unroll
    for (int mf = 0; mf < 2; ++mf)
#pragma unroll
        for (int ks = 0; ks < 2; ++ks)
            avf[mf][ks] = *(const bf16x8*)(avbf + (size_t)bh * 2048 + (mf * 16 + lr) * 64 + ks * 32 + g * 8);
    const int kst = h >> 1;
#pragma unroll 4
    for (int nf = 0; nf < 32; ++nf) {
        int j = nf * 16 + lr;
        bf16x8 w0 = *(const bf16x8*)(Wpt + (size_t)j * 512 + h * 64 + g * 8);
        bf16x8 w1 = *(const bf16x8*)(Wpt + (size_t)j * 512 + h * 64 + 32 + g * 8);
        int jt = j >> 7, row = j & 127;
#pragma unroll
        for (int mf = 0; mf < 2; ++mf) {
            f32x4 z = {0.f, 0.f, 0.f, 0.f};
            f32x4 acc = MFMA16(avf[mf][0], w0, z);
            acc = MFMA16(avf[mf][1], w1, acc);
            u16x4 o;
            o[0] = f2bf(acc[0]); o[1] = f2bf(acc[1]); o[2] = f2bf(acc[2]); o[3] = f2bf(acc[3]);
            int c8 = (h & 1) * 4 + mf * 2 + (g >> 1);
            size_t byte = ((size_t)((b * 4 + jt) * 4 + kst)) * 16384 + row * 128 +
                          ((c8 ^ (row & 7)) << 4) + (g & 1) * 8;
            *(u16x4*)(AVPt + byte) = o;
        }
    }
}

// ------------------------------- k_qattn ---------------------------------------
// MFMA q->agent softmax; writes Qattn TILED. grid 1024, block 256.
__global__ __launch_bounds__(256) void k_qattn(const unsigned short* __restrict__ Qbf,
                                               const unsigned short* __restrict__ abf,
                                               unsigned char* __restrict__ Qat) {
    const int tid = threadIdx.x, l = tid & 63, wid = tid >> 6;
    const int g = l >> 4, lr = l & 15;
    const int tok0 = blockIdx.x * 64;
#pragma unroll
    for (int hh = 0; hh < 2; ++hh) {
        const int h = wid * 2 + hh;
        bf16x8 af[2][2];
#pragma unroll
        for (int mf = 0; mf < 2; ++mf)
#pragma unroll
            for (int ks = 0; ks < 2; ++ks)
                af[mf][ks] = *(const bf16x8*)(abf + (size_t)h * 2048 + (mf * 16 + lr) * 64 + ks * 32 + g * 8);
        f32x4 acc[2][4] = {};
#pragma unroll
        for (int nf = 0; nf < 4; ++nf) {
            int tokn = tok0 + nf * 16 + lr;
            const unsigned short* qp = Qbf + (size_t)tokn * 512 + h * 64;
            bf16x8 q0 = *(const bf16x8*)(qp + g * 8);
            bf16x8 q1 = *(const bf16x8*)(qp + 32 + g * 8);
#pragma unroll
            for (int mf = 0; mf < 2; ++mf) {
                acc[mf][nf] = MFMA16(af[mf][0], q0, acc[mf][nf]);
                acc[mf][nf] = MFMA16(af[mf][1], q1, acc[mf][nf]);
            }
        }
        const int kst = h >> 1;
#pragma unroll
        for (int nf = 0; nf < 4; ++nf) {
            float mt = -3.0e38f;
#pragma unroll
            for (int s = 0; s < 8; ++s) mt = fmaxf(mt, acc[s >> 2][nf][s & 3] * 0.125f);
            mt = fmaxf(mt, __shfl_xor(mt, 16));
            mt = fmaxf(mt, __shfl_xor(mt, 32));
            float e[8], sum = 0.f;
#pragma unroll
            for (int s = 0; s < 8; ++s) {
                e[s] = __expf(acc[s >> 2][nf][s & 3] * 0.125f - mt);
                sum += e[s];
            }
            sum += __shfl_xor(sum, 16);
            sum += __shfl_xor(sum, 32);
            float inv = 1.0f / sum;
            int tokn = tok0 + nf * 16 + lr;
            int mtile = tokn >> 7, row = tokn & 127;
#pragma unroll
            for (int mf = 0; mf < 2; ++mf) {
                u16x4 o;
#pragma unroll
                for (int r = 0; r < 4; ++r) o[r] = f2bf(e[mf * 4 + r] * inv);
                int c8 = (h & 1) * 4 + mf * 2 + (g >> 1);
                size_t byte = ((size_t)(mtile * 4 + kst)) * 16384 + row * 128 +
                              ((c8 ^ (row & 7)) << 4) + (g & 1) * 8;
                *(u16x4*)(Qat + byte) = o;
            }
        }
    }
}

// ------------------------------- k_out -----------------------------------------
// BM=128, BN=128, BK=64, K=256; gload_lds staging of tiled Qattn/AVPt.
// grid 2048 (XCD-swizzled), block 256, waves 2x2 (64x64 each).
__global__ __launch_bounds__(256) void k_out(const unsigned char* __restrict__ Qat,
                                             const unsigned char* __restrict__ AVPt,
                                             const int* __restrict__ mask,
                                             float* __restrict__ out) {
    __shared__ __align__(16) unsigned char As[16384];
    __shared__ __align__(16) unsigned char Bs[16384];
    const int tid = threadIdx.x, l = tid & 63, wid = tid >> 6;
    const int wm = wid >> 1, wn = wid & 1;
    const int g = l >> 4, lr = l & 15;
    const int d = blockIdx.x;
    const int nt = (d >> 3) & 3;
    const int mt = (d & 7) + ((d >> 5) << 3);
    const int m0 = mt * 128, j0 = nt * 128;
    const int b = m0 >> 14;
    f32x4 acc[4][4] = {};

    for (int ks = 0; ks < 4; ++ks) {
        const size_t abase = ((size_t)(mt * 4 + ks)) * 16384;
        const size_t bbase = ((size_t)((b * 4 + nt) * 4 + ks)) * 16384;
#pragma unroll
        for (int i = 0; i < 4; ++i) {
            gl2lds16(Qat + abase + i * 4096 + tid * 16, As + i * 4096 + tid * 16);
            gl2lds16(AVPt + bbase + i * 4096 + tid * 16, Bs + i * 4096 + tid * 16);
        }
        __syncthreads();
        bf16x8 af[4][2];
#pragma unroll
        for (int mf = 0; mf < 4; ++mf) {
            int row = wm * 64 + mf * 16 + lr;
#pragma unroll
            for (int k2 = 0; k2 < 2; ++k2)
                af[mf][k2] = *(const bf16x8*)(As + row * 128 + (((k2 * 4 + g) ^ (row & 7)) << 4));
        }
#pragma unroll
        for (int k2 = 0; k2 < 2; ++k2) {
#pragma unroll
            for (int nf = 0; nf < 4; ++nf) {
                int brow = wn * 64 + nf * 16 + lr;
                bf16x8 bv = *(const bf16x8*)(Bs + brow * 128 + (((k2 * 4 + g) ^ (brow & 7)) << 4));
#pragma unroll
                for (int mf = 0; mf < 4; ++mf)
                    acc[mf][nf] = MFMA16(af[mf][k2], bv, acc[mf][nf]);
            }
        }
        __syncthreads();
    }
#pragma unroll
    for (int mf = 0; mf < 4; ++mf) {
        int trow = m0 + wm * 64 + mf * 16 + g * 4;
#pragma unroll
        for (int r = 0; r < 4; ++r) {
            float mv = (mask[trow + r] > 0) ? 1.0f : 0.0f;
#pragma unroll
            for (int nf = 0; nf < 4; ++nf) {
                int j = j0 + wn * 64 + nf * 16 + lr;
                out[(size_t)(trow + r) * 512 + j] = acc[mf][nf][r] * mv;
            }
        }
    }
}

// ------------------------------- launch -----------------------------------------
extern "C" void kernel_launch(void* const* d_in, const int* in_sizes, int n_in,
                              void* d_out, int out_size, void* d_ws, size_t ws_size,
                              hipStream_t stream) {
    const float* x  = (const float*)d_in[0];
    const int*  mk  = (const int*)d_in[1];
    const float* at = (const float*)d_in[2];
    const float* Wq = (const float*)d_in[3];
    const float* Wk = (const float*)d_in[4];
    const float* Wv = (const float*)d_in[5];
    const float* Wp = (const float*)d_in[6];
    float* out = (float*)d_out;
    char* ws = (char*)d_ws;

    unsigned char*  xt    = (unsigned char*)(ws);                        // [0,64) MiB tiled x (dead after k_qkv)
    unsigned short* Kbf   = (unsigned short*)(ws + ((size_t)64 << 20));  // [64,128)
    unsigned short* Vt    = (unsigned short*)(ws + ((size_t)128 << 20)); // [128,192)
    unsigned short* Qbf   = (unsigned short*)(ws + ((size_t)192 << 20)); // [192,256)
    unsigned short* Wt    = (unsigned short*)(ws + ((size_t)256 << 20)); // [256,258) row-major
    unsigned char*  wtl   = (unsigned char*)(ws + ((size_t)258 << 20));  // [258,259.5) tiled QKV weights
    unsigned short* abf   = (unsigned short*)(ws + ((size_t)259 << 20) + (512 << 10)); // 259.5 MiB, 32 KiB
    unsigned short* avbf  = (unsigned short*)(ws + ((size_t)259 << 20) + (576 << 10)); // +128 KiB
    unsigned char*  AVPt  = (unsigned char*)(ws + ((size_t)260 << 20));  // [260,261) tiled
    // aliases into the dead xt region:
    unsigned char*  Qat   = xt;                                          // [0,32) MiB tiled
    float* part_pv = (float*)(ws + ((size_t)32 << 20));                  // [32,48.8) MiB
    float* part_ml = (float*)(ws + ((size_t)52 << 20));                  // [52,52.5) MiB

    k_cvt_x<<<16384, 256, 0, stream>>>(x, xt);
    k_w_t<<<dim3(16, 16, 4), 256, 0, stream>>>(Wq, Wk, Wv, Wp, Wt);
    k_w_tile<<<dim3(8, 8, 3), 256, 0, stream>>>(Wq, Wk, Wv, wtl);
    k_pack_a<<<64, 256, 0, stream>>>(at, abf);
    k_qkv<<<4096, 256, 0, stream>>>(xt, wtl, Qbf, Kbf, Vt);
    k_agent_part<<<dim3(64, 32), 256, 0, stream>>>(Kbf, Vt, abf, mk, part_pv, part_ml);
    k_agent_comb<<<dim3(8, 32), 256, 0, stream>>>(part_pv, part_ml, avbf);
    k_avp<<<32, 64, 0, stream>>>(avbf, Wt + 786432, AVPt);
    k_qattn<<<1024, 256, 0, stream>>>(Qbf, abf, Qat);
    k_out<<<2048, 256, 0, stream>>>(Qat, AVPt, mk, out);
}